// Round 9
// baseline (11124.207 us; speedup 1.0000x reference)
//
#include <hip/hip_runtime.h>
#include <hip/hip_bf16.h>
#include <stdint.h>

// PRNG fork: partitionable (modern JAX default). Output dtype: FLOAT32
#define JAX_PARTITIONABLE 1

#define Bz 512
#define INz 256
#define Ez 256
#define Hz 512
#define Vz 32000
#define Tz 32
#define BTz (Bz * Tz)
#define TINYF 1.17549435e-38f

typedef float otype;
__device__ __forceinline__ void store_out(otype* out, int idx, float v) {
  out[idx] = v;
}

// ---------------- threefry2x32 (exact JAX semantics) ----------------
__device__ __forceinline__ uint32_t rotl32(uint32_t x, int r) {
  return (x << r) | (x >> (32 - r));
}
__device__ __forceinline__ void threefry2x32(uint32_t k0, uint32_t k1,
                                             uint32_t x0, uint32_t x1,
                                             uint32_t& o0, uint32_t& o1) {
  const uint32_t ks2 = k0 ^ k1 ^ 0x1BD11BDAu;
  x0 += k0; x1 += k1;
#define TF_R4(a, b, c, d)                              \
  x0 += x1; x1 = rotl32(x1, a); x1 ^= x0;              \
  x0 += x1; x1 = rotl32(x1, b); x1 ^= x0;              \
  x0 += x1; x1 = rotl32(x1, c); x1 ^= x0;              \
  x0 += x1; x1 = rotl32(x1, d); x1 ^= x0;
  TF_R4(13, 15, 26, 6)  x0 += k1;  x1 += ks2 + 1u;
  TF_R4(17, 29, 16, 24) x0 += ks2; x1 += k0 + 2u;
  TF_R4(13, 15, 26, 6)  x0 += k0;  x1 += k1 + 3u;
  TF_R4(17, 29, 16, 24) x0 += k1;  x1 += ks2 + 4u;
  TF_R4(13, 15, 26, 6)  x0 += ks2; x1 += k0 + 5u;
#undef TF_R4
  o0 = x0; o1 = x1;
}
__device__ __forceinline__ uint32_t rand_bits32(uint32_t ka, uint32_t kb,
                                                uint32_t idx, uint32_t n) {
#if JAX_PARTITIONABLE
  (void)n;
  uint32_t o0, o1;
  threefry2x32(ka, kb, 0u, idx, o0, o1);
  return o0 ^ o1;
#else
  uint32_t half = n >> 1;
  uint32_t o0, o1;
  if (idx < half) { threefry2x32(ka, kb, idx, idx + half, o0, o1); return o0; }
  threefry2x32(ka, kb, idx - half, idx, o0, o1); return o1;
#endif
}
__device__ __forceinline__ float bits_to_f01(uint32_t bits) {
  return __uint_as_float((bits >> 9) | 0x3f800000u) - 1.0f;
}

// ---------------- named kernel (template symbol, unused) ----------------
__global__ void RnnSenderReinforce_36799279792759_kernel(otype* __restrict__ out,
                                                         int n, float v) {
  int i = blockIdx.x * 256 + threadIdx.x;
  if (i < n) out[i] = v;
}

// ---------------- key schedule: keys[t] = [k1a,k1b,k2a,k2b] ----------------
__global__ void keys_kernel(uint32_t* __restrict__ keys) {
  int t = threadIdx.x;
  if (t >= Tz) return;
  uint32_t ka, kb;
#if JAX_PARTITIONABLE
  threefry2x32(0u, 42u, 0u, (uint32_t)t, ka, kb);
#else
  {
    uint32_t j0 = 2u * t, j1 = 2u * t + 1u;
    uint32_t a0, a1, b0, b1;
    if (j0 < Tz) { threefry2x32(0u, 42u, j0, j0 + Tz, a0, a1); ka = a0; }
    else         { threefry2x32(0u, 42u, j0 - Tz, j0, a0, a1); ka = a1; }
    if (j1 < Tz) { threefry2x32(0u, 42u, j1, j1 + Tz, b0, b1); kb = b0; }
    else         { threefry2x32(0u, 42u, j1 - Tz, j1, b0, b1); kb = b1; }
  }
#endif
  uint32_t o0, o1;
#if JAX_PARTITIONABLE
  threefry2x32(ka, kb, 0u, 0u, o0, o1);
  keys[t * 4 + 0] = o0; keys[t * 4 + 1] = o1;
  threefry2x32(ka, kb, 0u, 1u, o0, o1);
  keys[t * 4 + 2] = o0; keys[t * 4 + 3] = o1;
#else
  uint32_t p0, p1, q0, q1;
  threefry2x32(ka, kb, 0u, 2u, p0, p1);
  threefry2x32(ka, kb, 1u, 3u, q0, q1);
  keys[t * 4 + 0] = p0; keys[t * 4 + 1] = q0;
  keys[t * 4 + 2] = p1; keys[t * 4 + 3] = q1;
#endif
}

// ---------------- fp32 GEMM body (64x64 tile): C = A @ W^T + bias ----------
#define GBM 64
#define GBN 64
#define GBK 32
#define LDSS 68

__device__ __forceinline__ void gemm_bt_body(const float* __restrict__ A,
                                             const float* __restrict__ W,
                                             const float* __restrict__ bias,
                                             float* __restrict__ C,
                                             int M, int N, int K,
                                             int bx, int by,
                                             float* As, float* Bs) {
  const int tid = threadIdx.x;
  const int tx = tid & 15;
  const int ty = tid >> 4;
  const int m0 = by * GBM;
  const int n0 = bx * GBN;
  const int lr = tid >> 3;
  const int lc = (tid & 7) << 2;

  float acc[4][4] = {};
  const float* Ap = A + (size_t)(m0 + lr) * K + lc;
  const float* Wp = W + (size_t)(n0 + lr) * K + lc;
  const size_t rstep = (size_t)32 * K;

  for (int k0 = 0; k0 < K; k0 += GBK) {
    float4 a0 = *(const float4*)(Ap + k0);
    float4 a1 = *(const float4*)(Ap + k0 + rstep);
    float4 b0 = *(const float4*)(Wp + k0);
    float4 b1 = *(const float4*)(Wp + k0 + rstep);
    __syncthreads();
    As[(lc + 0) * LDSS + lr] = a0.x;
    As[(lc + 1) * LDSS + lr] = a0.y;
    As[(lc + 2) * LDSS + lr] = a0.z;
    As[(lc + 3) * LDSS + lr] = a0.w;
    As[(lc + 0) * LDSS + lr + 32] = a1.x;
    As[(lc + 1) * LDSS + lr + 32] = a1.y;
    As[(lc + 2) * LDSS + lr + 32] = a1.z;
    As[(lc + 3) * LDSS + lr + 32] = a1.w;
    Bs[(lc + 0) * LDSS + lr] = b0.x;
    Bs[(lc + 1) * LDSS + lr] = b0.y;
    Bs[(lc + 2) * LDSS + lr] = b0.z;
    Bs[(lc + 3) * LDSS + lr] = b0.w;
    Bs[(lc + 0) * LDSS + lr + 32] = b1.x;
    Bs[(lc + 1) * LDSS + lr + 32] = b1.y;
    Bs[(lc + 2) * LDSS + lr + 32] = b1.z;
    Bs[(lc + 3) * LDSS + lr + 32] = b1.w;
    __syncthreads();
#pragma unroll
    for (int kk = 0; kk < GBK; kk++) {
      float4 af = *(const float4*)&As[kk * LDSS + (ty << 2)];
      float4 bf = *(const float4*)&Bs[kk * LDSS + (tx << 2)];
      float ar[4] = {af.x, af.y, af.z, af.w};
      float br[4] = {bf.x, bf.y, bf.z, bf.w};
#pragma unroll
      for (int i = 0; i < 4; i++)
#pragma unroll
        for (int j = 0; j < 4; j++)
          acc[i][j] = fmaf(ar[i], br[j], acc[i][j]);
    }
  }

  const int nc = n0 + (tx << 2);
  float4 bv;
  bv.x = bias[nc + 0]; bv.y = bias[nc + 1]; bv.z = bias[nc + 2]; bv.w = bias[nc + 3];
#pragma unroll
  for (int i = 0; i < 4; i++) {
    int m = m0 + (ty << 2) + i;
    float4 o;
    o.x = acc[i][0] + bv.x;
    o.y = acc[i][1] + bv.y;
    o.z = acc[i][2] + bv.z;
    o.w = acc[i][3] + bv.w;
    *(float4*)(C + (size_t)m * N + nc) = o;
  }
}

__global__ __launch_bounds__(256) void gemm_bt(const float* __restrict__ A,
                                               const float* __restrict__ W,
                                               const float* __restrict__ bias,
                                               float* __restrict__ C,
                                               int M, int N, int K) {
  __shared__ __align__(16) float As[GBK * LDSS];
  __shared__ __align__(16) float Bs[GBK * LDSS];
  gemm_bt_body(A, W, bias, C, M, N, K, blockIdx.x, blockIdx.y, As, Bs);
}

// Fused gi/gh GEMM: blockIdx.z selects operand set (both depend only on
// prev-step state -> independent). Same body -> bit-identical results.
__global__ __launch_bounds__(256) void gru2_kernel(const float* __restrict__ inp,
                                                   const float* __restrict__ Wih,
                                                   const float* __restrict__ bih,
                                                   float* __restrict__ gi,
                                                   const float* __restrict__ h,
                                                   const float* __restrict__ Whh,
                                                   const float* __restrict__ bhh,
                                                   float* __restrict__ gh) {
  __shared__ __align__(16) float As[GBK * LDSS];
  __shared__ __align__(16) float Bs[GBK * LDSS];
  if (blockIdx.z == 0)
    gemm_bt_body(inp, Wih, bih, gi, Bz, 3 * Hz, Ez, blockIdx.x, blockIdx.y, As, Bs);
  else
    gemm_bt_body(h, Whh, bhh, gh, Bz, 3 * Hz, Hz, blockIdx.x, blockIdx.y, As, Bs);
}

// ------ fp32 GEMM (256x128, 512 thr, 8x8) + FUSED gumbel-argmax partials ----
// GEMM inner loop frozen at the best-measured config (201-216 us across 8
// variants). New: the epilogue computes pass-1 sampling partials for its
// 128-column panel. Valid because pass-1's result is the lexicographic max
// of (val,-idx) plus a set-max m -- semilattice ops, partition-independent,
// so per-panel partials fold to bit-identical results. l is computed with
// the same acc+bias expression as the stored logit (bit-equal); the
// threefry/gumbel chain is the identical code. As/Bs are dead post-K-loop
// and are reused as reduction scratch.
#define QBM 256
#define QBN 128
#define QBK 32
#define QLDA 260  // 256 + 4 pad
#define QLDB 132  // 128 + 4 pad

__global__ __launch_bounds__(512, 4) void gemm256_fused(
    const float* __restrict__ A, const float* __restrict__ W,
    const float* __restrict__ bias, float* __restrict__ C,
    const uint32_t* __restrict__ keys, int t,
    float* __restrict__ pv, int* __restrict__ pi,
    float* __restrict__ pl, float* __restrict__ pmx,
    int M, int N, int K) {
  __shared__ __align__(16) float As[QBK * QLDA];
  __shared__ __align__(16) float Bs[QBK * QLDB];
  const int tid = threadIdx.x;
  const int tx = tid & 15;   // n: cols tx*4..+3 and tx*4+64..+67
  const int ty = tid >> 4;   // m: rows ty*4..+3 and ty*4+128..+131

  // XCD-aware bijective remap for grid 500 = 250 panels x 2 m-tiles.
  const int nP = N / QBN;    // 250
  const int G = nP >> 3;     // 31 full groups of 8 panels
  const int lim = G << 4;    // 496
  int b = blockIdx.x;
  int P, mi;
  if (b < lim) {
    int g = b >> 4, r = b & 15;
    mi = r >> 3;
    P = (g << 3) + (r & 7);
  } else {
    int e = b - lim;
    P = (G << 3) + (e & 1);
    mi = e >> 1;
  }
  const int m0 = mi * QBM;
  const int n0 = P * QBN;

  // A staging: thread -> row ar = tid>>1 (0..255), 4 float4 at k = ak..ak+15
  const int ar = tid >> 1;
  const int ak = (tid & 1) << 4;   // 0 or 16
  // B staging: row br = tid>>2 (0..127), float4 at bk and bk+16
  const int br = tid >> 2;
  const int bk = (tid & 3) << 2;   // 0,4,8,12

  const float* Ap = A + (size_t)(m0 + ar) * K + ak;
  const float* Wp = W + (size_t)(n0 + br) * K + bk;

  float4 a0 = *(const float4*)(Ap);
  float4 a1 = *(const float4*)(Ap + 4);
  float4 a2 = *(const float4*)(Ap + 8);
  float4 a3 = *(const float4*)(Ap + 12);
  float4 b0 = *(const float4*)(Wp);
  float4 b1 = *(const float4*)(Wp + 16);

  float acc[8][8] = {};

  for (int k0 = 0; k0 < K; k0 += QBK) {
    __syncthreads();
    As[(ak + 0) * QLDA + ar] = a0.x;
    As[(ak + 1) * QLDA + ar] = a0.y;
    As[(ak + 2) * QLDA + ar] = a0.z;
    As[(ak + 3) * QLDA + ar] = a0.w;
    As[(ak + 4) * QLDA + ar] = a1.x;
    As[(ak + 5) * QLDA + ar] = a1.y;
    As[(ak + 6) * QLDA + ar] = a1.z;
    As[(ak + 7) * QLDA + ar] = a1.w;
    As[(ak + 8) * QLDA + ar] = a2.x;
    As[(ak + 9) * QLDA + ar] = a2.y;
    As[(ak + 10) * QLDA + ar] = a2.z;
    As[(ak + 11) * QLDA + ar] = a2.w;
    As[(ak + 12) * QLDA + ar] = a3.x;
    As[(ak + 13) * QLDA + ar] = a3.y;
    As[(ak + 14) * QLDA + ar] = a3.z;
    As[(ak + 15) * QLDA + ar] = a3.w;
    Bs[(bk + 0) * QLDB + br] = b0.x;
    Bs[(bk + 1) * QLDB + br] = b0.y;
    Bs[(bk + 2) * QLDB + br] = b0.z;
    Bs[(bk + 3) * QLDB + br] = b0.w;
    Bs[(16 + bk + 0) * QLDB + br] = b1.x;
    Bs[(16 + bk + 1) * QLDB + br] = b1.y;
    Bs[(16 + bk + 2) * QLDB + br] = b1.z;
    Bs[(16 + bk + 3) * QLDB + br] = b1.w;
    __syncthreads();
    if (k0 + QBK < K) {
      a0 = *(const float4*)(Ap + k0 + QBK);
      a1 = *(const float4*)(Ap + k0 + QBK + 4);
      a2 = *(const float4*)(Ap + k0 + QBK + 8);
      a3 = *(const float4*)(Ap + k0 + QBK + 12);
      b0 = *(const float4*)(Wp + k0 + QBK);
      b1 = *(const float4*)(Wp + k0 + QBK + 16);
    }
#pragma unroll 4
    for (int kk = 0; kk < QBK; kk++) {
      float4 xa0 = *(const float4*)&As[kk * QLDA + (ty << 2)];
      float4 xa1 = *(const float4*)&As[kk * QLDA + 128 + (ty << 2)];
      float4 xb0 = *(const float4*)&Bs[kk * QLDB + (tx << 2)];
      float4 xb1 = *(const float4*)&Bs[kk * QLDB + 64 + (tx << 2)];
      float ar8[8] = {xa0.x, xa0.y, xa0.z, xa0.w, xa1.x, xa1.y, xa1.z, xa1.w};
      float br8[8] = {xb0.x, xb0.y, xb0.z, xb0.w, xb1.x, xb1.y, xb1.z, xb1.w};
#pragma unroll
      for (int i = 0; i < 8; i++)
#pragma unroll
        for (int j = 0; j < 8; j++)
          acc[i][j] = fmaf(ar8[i], br8[j], acc[i][j]);
    }
  }

  const int nc0 = n0 + (tx << 2);
  const float4 bv0 = *(const float4*)(bias + nc0);
  const float4 bv1 = *(const float4*)(bias + nc0 + 64);

  // LDS reduction scratch (As/Bs dead after last compute + barrier below)
  __syncthreads();
  float* vval = As;                       // [256][16] floats (16 KB)
  int*   vidx = (int*)(As + 256 * 16);    // [256][16] ints   (16 KB) <= 33280 B
  float* vlgt = Bs;                       // [256][16] floats (16 KB) <= 16896 B
  const uint32_t k1a = keys[t * 4 + 0], k1b = keys[t * 4 + 1];
  float pmt[8];

#pragma unroll
  for (int hf = 0; hf < 2; hf++) {
#pragma unroll
    for (int i = 0; i < 4; i++) {
      const int r = hf * 128 + (ty << 2) + i;
      const int m = m0 + r;
      float* Cp = C + (size_t)m * N + nc0;
      float4 o;
      o.x = acc[hf * 4 + i][0] + bv0.x;
      o.y = acc[hf * 4 + i][1] + bv0.y;
      o.z = acc[hf * 4 + i][2] + bv0.z;
      o.w = acc[hf * 4 + i][3] + bv0.w;
      *(float4*)Cp = o;
      float4 o2;
      o2.x = acc[hf * 4 + i][4] + bv1.x;
      o2.y = acc[hf * 4 + i][5] + bv1.y;
      o2.z = acc[hf * 4 + i][6] + bv1.z;
      o2.w = acc[hf * 4 + i][7] + bv1.w;
      *(float4*)(Cp + 64) = o2;

      // fused pass-1 over this row's 8 columns (ascending v)
      const uint32_t base = (uint32_t)m * (uint32_t)Vz;
      float lv[8] = {o.x, o.y, o.z, o.w, o2.x, o2.y, o2.z, o2.w};
      float best = -INFINITY, blgt = 0.0f, mrow = -INFINITY;
      int bidx = 0x7FFFFFFF;
#pragma unroll
      for (int j = 0; j < 8; j++) {
        const int v = (j < 4) ? (nc0 + j) : (nc0 + 64 + j - 4);
        float l = lv[j];
        mrow = fmaxf(mrow, l);
        uint32_t bits = rand_bits32(k1a, k1b, base + (uint32_t)v,
                                    (uint32_t)Bz * Vz);
        float f = bits_to_f01(bits);
        float u = fmaxf(TINYF, f + TINYF);   // uniform(minval=tiny)
        float g = -logf(-logf(u));           // gumbel
        float val = l + g;
        if (val > best) { best = val; bidx = v; blgt = l; }
      }
      vval[r * 16 + tx] = best;
      vidx[r * 16 + tx] = bidx;
      vlgt[r * 16 + tx] = blgt;
      pmt[hf * 4 + i] = mrow;
    }
  }
  __syncthreads();
  // row-reduce across the 16 tx slots with the exact (>, min-idx) rule
  float rbest = 0.0f, rlgt = 0.0f;
  int ridx = 0;
  if (tid < 256) {
    rbest = vval[tid * 16]; ridx = vidx[tid * 16]; rlgt = vlgt[tid * 16];
#pragma unroll
    for (int x = 1; x < 16; x++) {
      float go = vval[tid * 16 + x]; int io = vidx[tid * 16 + x];
      if (go > rbest || (go == rbest && io < ridx)) {
        rbest = go; ridx = io; rlgt = vlgt[tid * 16 + x];
      }
    }
  }
  __syncthreads();
  // m reduction (reuse vval)
#pragma unroll
  for (int s = 0; s < 8; s++) {
    const int r = (s >> 2) * 128 + (ty << 2) + (s & 3);
    vval[r * 16 + tx] = pmt[s];
  }
  __syncthreads();
  if (tid < 256) {
    float mr = vval[tid * 16];
#pragma unroll
    for (int x = 1; x < 16; x++) mr = fmaxf(mr, vval[tid * 16 + x]);
    const int o = (m0 + tid) * 256 + P;   // [b][P] layout, P padded to 256
    pv[o] = rbest; pi[o] = ridx; pl[o] = rlgt; pmx[o] = mr;
  }
}

// ---------------- GRU gates + fused stop head ----------------
__global__ __launch_bounds__(512) void gates_stop_kernel(
    const float* __restrict__ gi, const float* __restrict__ gh,
    float* __restrict__ h, const float* __restrict__ W_stop,
    const float* __restrict__ b_stop, const uint32_t* __restrict__ keys,
    int t, otype* __restrict__ out) {
  __shared__ float hrow[Hz];
  const int b = blockIdx.x;
  const int j = threadIdx.x;
  const float* gib = gi + (size_t)b * (3 * Hz);
  const float* ghb = gh + (size_t)b * (3 * Hz);
  float ir = gib[j], iz = gib[j + Hz], in_ = gib[j + 2 * Hz];
  float hr = ghb[j], hz = ghb[j + Hz], hn = ghb[j + 2 * Hz];
  float r = 1.0f / (1.0f + expf(-(ir + hr)));
  float z = 1.0f / (1.0f + expf(-(iz + hz)));
  float n = tanhf(in_ + r * hn);
  float hv = h[(size_t)b * Hz + j];
  float hnew = (1.0f - z) * n + z * hv;
  h[(size_t)b * Hz + j] = hnew;
  hrow[j] = hnew;
  __syncthreads();
  if (j < 64) {
    const int lane = j;
    float s = 0.0f;
    for (int k = lane; k < Hz; k += 64) s = fmaf(hrow[k], W_stop[k], s);
#pragma unroll
    for (int off = 32; off; off >>= 1) s += __shfl_down(s, off, 64);
    if (lane == 0) {
      s += b_stop[0];
      uint32_t bits = rand_bits32(keys[t * 4 + 2], keys[t * 4 + 3], (uint32_t)b, Bz);
      float u = bits_to_f01(bits);  // bernoulli: minval=0 -> u = f
      float p = 1.0f / (1.0f + expf(-s));
      float stop = (u < p) ? 1.0f : 0.0f;
      float sp = fmaxf(s, 0.0f) + log1pf(expf(-fabsf(s)));  // softplus
      store_out(out, 1 * BTz + b * Tz + t, stop);
      store_out(out, 3 * BTz + b * Tz + t, stop * s - sp);
      store_out(out, 5 * BTz + b * Tz + t, sp - s * p);
    }
  }
}

// ---- sample p2: fold panel partials, tree, log_softmax stats, gather ------
__global__ __launch_bounds__(256) void sample_p2(const float* __restrict__ logits,
                                                 const float* __restrict__ pv,
                                                 const int* __restrict__ pi,
                                                 const float* __restrict__ pl,
                                                 const float* __restrict__ pmx,
                                                 int t, otype* __restrict__ out,
                                                 const float* __restrict__ emb,
                                                 float* __restrict__ inp) {
  __shared__ float sm[256], sg[256], sgl[256], sz[256], ss[256];
  __shared__ int sgi[256];
  __shared__ int ssymb;
  const int tid = threadIdx.x;
  const int b = blockIdx.x;
  const float* lb = logits + (size_t)b * Vz;

  // load per-panel partials (sentinels for padded slots 250..255)
  float m = -INFINITY, gbest = -INFINITY, glogit = 0.0f;
  int gidx = 0x7FFFFFFF;
  if (tid < 250) {
    const int o = b * 256 + tid;
    m = pmx[o]; gbest = pv[o]; gidx = pi[o]; glogit = pl[o];
  }
  sm[tid] = m; sg[tid] = gbest; sgi[tid] = gidx; sgl[tid] = glogit;
  __syncthreads();
  // original 256-tree (exact comparator)
  for (int s2 = 128; s2; s2 >>= 1) {
    if (tid < s2) {
      sm[tid] = fmaxf(sm[tid], sm[tid + s2]);
      float go = sg[tid + s2]; int io = sgi[tid + s2];
      if (go > sg[tid] || (go == sg[tid] && io < sgi[tid])) {
        sg[tid] = go; sgi[tid] = io; sgl[tid] = sgl[tid + s2];
      }
    }
    __syncthreads();
  }
  const float M = sm[0];

  // pass 2: order-sensitive sums, byte-for-byte original
  float Z = 0.0f, S1 = 0.0f;
  for (int v = tid; v < Vz; v += 256) {
    float sft = lb[v] - M;
    float e = expf(sft);
    Z += e;
    S1 = fmaf(e, sft, S1);
  }
  sz[tid] = Z; ss[tid] = S1;
  __syncthreads();
  for (int s2 = 128; s2; s2 >>= 1) {
    if (tid < s2) { sz[tid] += sz[tid + s2]; ss[tid] += ss[tid + s2]; }
    __syncthreads();
  }
  if (tid == 0) {
    float Zt = sz[0], S1t = ss[0];
    float lse = logf(Zt);
    int symb = sgi[0];
    store_out(out, 0 * BTz + b * Tz + t, (float)symb);
    store_out(out, 2 * BTz + b * Tz + t, (sgl[0] - M) - lse);
    store_out(out, 4 * BTz + b * Tz + t, lse - S1t / Zt);
    ssymb = symb;
  }
  __syncthreads();
  int s = ssymb;
  s = (s < 0) ? 0 : ((s >= Vz) ? (Vz - 1) : s);
  inp[(size_t)b * Ez + tid] = emb[(size_t)s * Ez + tid];
}

// ---------------- misc ----------------
__global__ void init_inp_kernel(float* __restrict__ inp, const float* __restrict__ sos) {
  inp[blockIdx.x * Ez + threadIdx.x] = sos[threadIdx.x];
}

// ---------------- launch ----------------
extern "C" __attribute__((visibility("default")))
void kernel_launch(void* const* d_in, const int* in_sizes, int n_in,
                   void* d_out, int out_size, void* d_ws, size_t ws_size,
                   hipStream_t stream) {
  const float* x       = (const float*)d_in[0];
  const float* agent_w = (const float*)d_in[1];
  const float* agent_b = (const float*)d_in[2];
  const float* sos     = (const float*)d_in[3];
  const float* emb     = (const float*)d_in[4];
  const float* W_ih    = (const float*)d_in[5];
  const float* W_hh    = (const float*)d_in[6];
  const float* b_ih    = (const float*)d_in[7];
  const float* b_hh    = (const float*)d_in[8];
  const float* W_out   = (const float*)d_in[9];
  const float* b_out   = (const float*)d_in[10];
  const float* W_stop  = (const float*)d_in[11];
  const float* b_stop  = (const float*)d_in[12];
  otype* out = (otype*)d_out;

  float* ws = (float*)d_ws;
  float* h      = ws;
  float* inp    = h + (size_t)Bz * Hz;
  float* gi     = inp + (size_t)Bz * Ez;
  float* gh     = gi + (size_t)Bz * 3 * Hz;
  float* logits = gh + (size_t)Bz * 3 * Hz;
  uint32_t* keys = (uint32_t*)(logits + (size_t)Bz * Vz);

  // panel-partial buffers alias gi (dead between gates_stop and next gru2):
  // 4 arrays of 512*256 = 131072 each -> 524288 floats <= gi's 786432.
  float* pv  = gi;
  int*   pi  = (int*)(gi + 131072);
  float* pl  = gi + 2 * 131072;
  float* pmx = gi + 3 * 131072;

  keys_kernel<<<1, 64, 0, stream>>>(keys);
  init_inp_kernel<<<Bz, Ez, 0, stream>>>(inp, sos);
  gemm_bt<<<dim3(Hz / GBN, Bz / GBM), 256, 0, stream>>>(x, agent_w, agent_b, h,
                                                        Bz, Hz, INz);
  for (int t = 0; t < Tz; t++) {
    gru2_kernel<<<dim3(3 * Hz / GBN, Bz / GBM, 2), 256, 0, stream>>>(
        inp, W_ih, b_ih, gi, h, W_hh, b_hh, gh);
    gates_stop_kernel<<<Bz, 512, 0, stream>>>(gi, gh, h, W_stop, b_stop, keys,
                                              t, out);
    gemm256_fused<<<(Vz / QBN) * (Bz / QBM), 512, 0, stream>>>(
        h, W_out, b_out, logits, keys, t, pv, pi, pl, pmx, Bz, Vz, Hz);
    sample_p2<<<Bz, 256, 0, stream>>>(logits, pv, pi, pl, pmx, t, out, emb,
                                      inp);
  }
}

// Round 10
// 10207.004 us; speedup vs baseline: 1.0899x; 1.0899x over previous
//
#include <hip/hip_runtime.h>
#include <hip/hip_bf16.h>
#include <stdint.h>

// PRNG fork: partitionable (modern JAX default). Output dtype: FLOAT32
#define JAX_PARTITIONABLE 1

#define Bz 512
#define INz 256
#define Ez 256
#define Hz 512
#define Vz 32000
#define Tz 32
#define BTz (Bz * Tz)
#define TINYF 1.17549435e-38f

typedef float otype;
__device__ __forceinline__ void store_out(otype* out, int idx, float v) {
  out[idx] = v;
}

// ---------------- threefry2x32 (exact JAX semantics) ----------------
__device__ __forceinline__ uint32_t rotl32(uint32_t x, int r) {
  return (x << r) | (x >> (32 - r));
}
__device__ __forceinline__ void threefry2x32(uint32_t k0, uint32_t k1,
                                             uint32_t x0, uint32_t x1,
                                             uint32_t& o0, uint32_t& o1) {
  const uint32_t ks2 = k0 ^ k1 ^ 0x1BD11BDAu;
  x0 += k0; x1 += k1;
#define TF_R4(a, b, c, d)                              \
  x0 += x1; x1 = rotl32(x1, a); x1 ^= x0;              \
  x0 += x1; x1 = rotl32(x1, b); x1 ^= x0;              \
  x0 += x1; x1 = rotl32(x1, c); x1 ^= x0;              \
  x0 += x1; x1 = rotl32(x1, d); x1 ^= x0;
  TF_R4(13, 15, 26, 6)  x0 += k1;  x1 += ks2 + 1u;
  TF_R4(17, 29, 16, 24) x0 += ks2; x1 += k0 + 2u;
  TF_R4(13, 15, 26, 6)  x0 += k0;  x1 += k1 + 3u;
  TF_R4(17, 29, 16, 24) x0 += k1;  x1 += ks2 + 4u;
  TF_R4(13, 15, 26, 6)  x0 += ks2; x1 += k0 + 5u;
#undef TF_R4
  o0 = x0; o1 = x1;
}
__device__ __forceinline__ uint32_t rand_bits32(uint32_t ka, uint32_t kb,
                                                uint32_t idx, uint32_t n) {
#if JAX_PARTITIONABLE
  (void)n;
  uint32_t o0, o1;
  threefry2x32(ka, kb, 0u, idx, o0, o1);
  return o0 ^ o1;
#else
  uint32_t half = n >> 1;
  uint32_t o0, o1;
  if (idx < half) { threefry2x32(ka, kb, idx, idx + half, o0, o1); return o0; }
  threefry2x32(ka, kb, idx - half, idx, o0, o1); return o1;
#endif
}
__device__ __forceinline__ float bits_to_f01(uint32_t bits) {
  return __uint_as_float((bits >> 9) | 0x3f800000u) - 1.0f;
}

// ---------------- named kernel (template symbol, unused) ----------------
__global__ void RnnSenderReinforce_36799279792759_kernel(otype* __restrict__ out,
                                                         int n, float v) {
  int i = blockIdx.x * 256 + threadIdx.x;
  if (i < n) out[i] = v;
}

// ---------------- key schedule: keys[t] = [k1a,k1b,k2a,k2b] ----------------
__global__ void keys_kernel(uint32_t* __restrict__ keys) {
  int t = threadIdx.x;
  if (t >= Tz) return;
  uint32_t ka, kb;
#if JAX_PARTITIONABLE
  threefry2x32(0u, 42u, 0u, (uint32_t)t, ka, kb);
#else
  {
    uint32_t j0 = 2u * t, j1 = 2u * t + 1u;
    uint32_t a0, a1, b0, b1;
    if (j0 < Tz) { threefry2x32(0u, 42u, j0, j0 + Tz, a0, a1); ka = a0; }
    else         { threefry2x32(0u, 42u, j0 - Tz, j0, a0, a1); ka = a1; }
    if (j1 < Tz) { threefry2x32(0u, 42u, j1, j1 + Tz, b0, b1); kb = b0; }
    else         { threefry2x32(0u, 42u, j1 - Tz, j1, b0, b1); kb = b1; }
  }
#endif
  uint32_t o0, o1;
#if JAX_PARTITIONABLE
  threefry2x32(ka, kb, 0u, 0u, o0, o1);
  keys[t * 4 + 0] = o0; keys[t * 4 + 1] = o1;
  threefry2x32(ka, kb, 0u, 1u, o0, o1);
  keys[t * 4 + 2] = o0; keys[t * 4 + 3] = o1;
#else
  uint32_t p0, p1, q0, q1;
  threefry2x32(ka, kb, 0u, 2u, p0, p1);
  threefry2x32(ka, kb, 1u, 3u, q0, q1);
  keys[t * 4 + 0] = p0; keys[t * 4 + 1] = q0;
  keys[t * 4 + 2] = p1; keys[t * 4 + 3] = q1;
#endif
}

// ---------------- fp32 GEMM body (64x64 tile): C = A @ W^T + bias ----------
#define GBM 64
#define GBN 64
#define GBK 32
#define LDSS 68

__device__ __forceinline__ void gemm_bt_body(const float* __restrict__ A,
                                             const float* __restrict__ W,
                                             const float* __restrict__ bias,
                                             float* __restrict__ C,
                                             int M, int N, int K,
                                             int bx, int by,
                                             float* As, float* Bs) {
  const int tid = threadIdx.x;
  const int tx = tid & 15;
  const int ty = tid >> 4;
  const int m0 = by * GBM;
  const int n0 = bx * GBN;
  const int lr = tid >> 3;
  const int lc = (tid & 7) << 2;

  float acc[4][4] = {};
  const float* Ap = A + (size_t)(m0 + lr) * K + lc;
  const float* Wp = W + (size_t)(n0 + lr) * K + lc;
  const size_t rstep = (size_t)32 * K;

  for (int k0 = 0; k0 < K; k0 += GBK) {
    float4 a0 = *(const float4*)(Ap + k0);
    float4 a1 = *(const float4*)(Ap + k0 + rstep);
    float4 b0 = *(const float4*)(Wp + k0);
    float4 b1 = *(const float4*)(Wp + k0 + rstep);
    __syncthreads();
    As[(lc + 0) * LDSS + lr] = a0.x;
    As[(lc + 1) * LDSS + lr] = a0.y;
    As[(lc + 2) * LDSS + lr] = a0.z;
    As[(lc + 3) * LDSS + lr] = a0.w;
    As[(lc + 0) * LDSS + lr + 32] = a1.x;
    As[(lc + 1) * LDSS + lr + 32] = a1.y;
    As[(lc + 2) * LDSS + lr + 32] = a1.z;
    As[(lc + 3) * LDSS + lr + 32] = a1.w;
    Bs[(lc + 0) * LDSS + lr] = b0.x;
    Bs[(lc + 1) * LDSS + lr] = b0.y;
    Bs[(lc + 2) * LDSS + lr] = b0.z;
    Bs[(lc + 3) * LDSS + lr] = b0.w;
    Bs[(lc + 0) * LDSS + lr + 32] = b1.x;
    Bs[(lc + 1) * LDSS + lr + 32] = b1.y;
    Bs[(lc + 2) * LDSS + lr + 32] = b1.z;
    Bs[(lc + 3) * LDSS + lr + 32] = b1.w;
    __syncthreads();
#pragma unroll
    for (int kk = 0; kk < GBK; kk++) {
      float4 af = *(const float4*)&As[kk * LDSS + (ty << 2)];
      float4 bf = *(const float4*)&Bs[kk * LDSS + (tx << 2)];
      float ar[4] = {af.x, af.y, af.z, af.w};
      float br[4] = {bf.x, bf.y, bf.z, bf.w};
#pragma unroll
      for (int i = 0; i < 4; i++)
#pragma unroll
        for (int j = 0; j < 4; j++)
          acc[i][j] = fmaf(ar[i], br[j], acc[i][j]);
    }
  }

  const int nc = n0 + (tx << 2);
  float4 bv;
  bv.x = bias[nc + 0]; bv.y = bias[nc + 1]; bv.z = bias[nc + 2]; bv.w = bias[nc + 3];
#pragma unroll
  for (int i = 0; i < 4; i++) {
    int m = m0 + (ty << 2) + i;
    float4 o;
    o.x = acc[i][0] + bv.x;
    o.y = acc[i][1] + bv.y;
    o.z = acc[i][2] + bv.z;
    o.w = acc[i][3] + bv.w;
    *(float4*)(C + (size_t)m * N + nc) = o;
  }
}

__global__ __launch_bounds__(256) void gemm_bt(const float* __restrict__ A,
                                               const float* __restrict__ W,
                                               const float* __restrict__ bias,
                                               float* __restrict__ C,
                                               int M, int N, int K) {
  __shared__ __align__(16) float As[GBK * LDSS];
  __shared__ __align__(16) float Bs[GBK * LDSS];
  gemm_bt_body(A, W, bias, C, M, N, K, blockIdx.x, blockIdx.y, As, Bs);
}

// Fused gi/gh GEMM: blockIdx.z selects operand set (both depend only on
// prev-step state -> independent). Same body -> bit-identical results.
__global__ __launch_bounds__(256) void gru2_kernel(const float* __restrict__ inp,
                                                   const float* __restrict__ Wih,
                                                   const float* __restrict__ bih,
                                                   float* __restrict__ gi,
                                                   const float* __restrict__ h,
                                                   const float* __restrict__ Whh,
                                                   const float* __restrict__ bhh,
                                                   float* __restrict__ gh) {
  __shared__ __align__(16) float As[GBK * LDSS];
  __shared__ __align__(16) float Bs[GBK * LDSS];
  if (blockIdx.z == 0)
    gemm_bt_body(inp, Wih, bih, gi, Bz, 3 * Hz, Ez, blockIdx.x, blockIdx.y, As, Bs);
  else
    gemm_bt_body(h, Whh, bhh, gh, Bz, 3 * Hz, Hz, blockIdx.x, blockIdx.y, As, Bs);
}

// ------- fp32 GEMM (256x128 tile, 512 thr, 8x8/thread): big logits GEMM -----
// Best-measured configuration (R3/R6: 201-207 us). Eight structural variants
// (tile/occupancy/dbuf/grid/fusion) all land 201-264 us -> this fp32 style is
// at ~51% of the 157 TF VALU peak, pinned by ds_read-instruction + staging +
// barrier overhead; bit-exactness (k-ascending single-accumulator fmaf; the
// Gumbel argmax yields INTEGER outputs, so no MFMA/split-K/precision tricks)
// rules out the remaining levers. Per-element fmaf chain -> bit-identical.
#define QBM 256
#define QBN 128
#define QBK 32
#define QLDA 260  // 256 + 4 pad
#define QLDB 132  // 128 + 4 pad

__global__ __launch_bounds__(512, 4) void gemm256_bt(const float* __restrict__ A,
                                                     const float* __restrict__ W,
                                                     const float* __restrict__ bias,
                                                     float* __restrict__ C,
                                                     int M, int N, int K) {
  __shared__ __align__(16) float As[QBK * QLDA];
  __shared__ __align__(16) float Bs[QBK * QLDB];
  const int tid = threadIdx.x;
  const int tx = tid & 15;   // n: cols tx*4..+3 and tx*4+64..+67
  const int ty = tid >> 4;   // m: rows ty*4..+3 and ty*4+128..+131

  // XCD-aware bijective remap for grid 500 = 250 panels x 2 m-tiles.
  // Same-panel pair gets ids differing by 8 -> same id%8 -> same XCD.
  const int nP = N / QBN;    // 250
  const int G = nP >> 3;     // 31 full groups of 8 panels
  const int lim = G << 4;    // 496
  int b = blockIdx.x;
  int P, mi;
  if (b < lim) {
    int g = b >> 4, r = b & 15;
    mi = r >> 3;
    P = (g << 3) + (r & 7);
  } else {
    int e = b - lim;
    P = (G << 3) + (e & 1);
    mi = e >> 1;
  }
  const int m0 = mi * QBM;
  const int n0 = P * QBN;

  // A staging: thread -> row ar = tid>>1 (0..255), 4 float4 at k = ak..ak+15
  const int ar = tid >> 1;
  const int ak = (tid & 1) << 4;   // 0 or 16
  // B staging: row br = tid>>2 (0..127), float4 at bk and bk+16
  const int br = tid >> 2;
  const int bk = (tid & 3) << 2;   // 0,4,8,12

  const float* Ap = A + (size_t)(m0 + ar) * K + ak;
  const float* Wp = W + (size_t)(n0 + br) * K + bk;

  float4 a0 = *(const float4*)(Ap);
  float4 a1 = *(const float4*)(Ap + 4);
  float4 a2 = *(const float4*)(Ap + 8);
  float4 a3 = *(const float4*)(Ap + 12);
  float4 b0 = *(const float4*)(Wp);
  float4 b1 = *(const float4*)(Wp + 16);

  float acc[8][8] = {};

  for (int k0 = 0; k0 < K; k0 += QBK) {
    __syncthreads();
    As[(ak + 0) * QLDA + ar] = a0.x;
    As[(ak + 1) * QLDA + ar] = a0.y;
    As[(ak + 2) * QLDA + ar] = a0.z;
    As[(ak + 3) * QLDA + ar] = a0.w;
    As[(ak + 4) * QLDA + ar] = a1.x;
    As[(ak + 5) * QLDA + ar] = a1.y;
    As[(ak + 6) * QLDA + ar] = a1.z;
    As[(ak + 7) * QLDA + ar] = a1.w;
    As[(ak + 8) * QLDA + ar] = a2.x;
    As[(ak + 9) * QLDA + ar] = a2.y;
    As[(ak + 10) * QLDA + ar] = a2.z;
    As[(ak + 11) * QLDA + ar] = a2.w;
    As[(ak + 12) * QLDA + ar] = a3.x;
    As[(ak + 13) * QLDA + ar] = a3.y;
    As[(ak + 14) * QLDA + ar] = a3.z;
    As[(ak + 15) * QLDA + ar] = a3.w;
    Bs[(bk + 0) * QLDB + br] = b0.x;
    Bs[(bk + 1) * QLDB + br] = b0.y;
    Bs[(bk + 2) * QLDB + br] = b0.z;
    Bs[(bk + 3) * QLDB + br] = b0.w;
    Bs[(16 + bk + 0) * QLDB + br] = b1.x;
    Bs[(16 + bk + 1) * QLDB + br] = b1.y;
    Bs[(16 + bk + 2) * QLDB + br] = b1.z;
    Bs[(16 + bk + 3) * QLDB + br] = b1.w;
    __syncthreads();
    if (k0 + QBK < K) {
      a0 = *(const float4*)(Ap + k0 + QBK);
      a1 = *(const float4*)(Ap + k0 + QBK + 4);
      a2 = *(const float4*)(Ap + k0 + QBK + 8);
      a3 = *(const float4*)(Ap + k0 + QBK + 12);
      b0 = *(const float4*)(Wp + k0 + QBK);
      b1 = *(const float4*)(Wp + k0 + QBK + 16);
    }
#pragma unroll 4
    for (int kk = 0; kk < QBK; kk++) {
      float4 xa0 = *(const float4*)&As[kk * QLDA + (ty << 2)];
      float4 xa1 = *(const float4*)&As[kk * QLDA + 128 + (ty << 2)];
      float4 xb0 = *(const float4*)&Bs[kk * QLDB + (tx << 2)];
      float4 xb1 = *(const float4*)&Bs[kk * QLDB + 64 + (tx << 2)];
      float ar8[8] = {xa0.x, xa0.y, xa0.z, xa0.w, xa1.x, xa1.y, xa1.z, xa1.w};
      float br8[8] = {xb0.x, xb0.y, xb0.z, xb0.w, xb1.x, xb1.y, xb1.z, xb1.w};
#pragma unroll
      for (int i = 0; i < 8; i++)
#pragma unroll
        for (int j = 0; j < 8; j++)
          acc[i][j] = fmaf(ar8[i], br8[j], acc[i][j]);
    }
  }

  const int nc0 = n0 + (tx << 2);
  const float4 bv0 = *(const float4*)(bias + nc0);
  const float4 bv1 = *(const float4*)(bias + nc0 + 64);
#pragma unroll
  for (int hf = 0; hf < 2; hf++) {
#pragma unroll
    for (int i = 0; i < 4; i++) {
      const int m = m0 + hf * 128 + (ty << 2) + i;
      float* Cp = C + (size_t)m * N + nc0;
      float4 o;
      o.x = acc[hf * 4 + i][0] + bv0.x;
      o.y = acc[hf * 4 + i][1] + bv0.y;
      o.z = acc[hf * 4 + i][2] + bv0.z;
      o.w = acc[hf * 4 + i][3] + bv0.w;
      *(float4*)Cp = o;
      float4 o2;
      o2.x = acc[hf * 4 + i][4] + bv1.x;
      o2.y = acc[hf * 4 + i][5] + bv1.y;
      o2.z = acc[hf * 4 + i][6] + bv1.z;
      o2.w = acc[hf * 4 + i][7] + bv1.w;
      *(float4*)(Cp + 64) = o2;
    }
  }
}

// ---------------- GRU gates + fused stop head ----------------
__global__ __launch_bounds__(512) void gates_stop_kernel(
    const float* __restrict__ gi, const float* __restrict__ gh,
    float* __restrict__ h, const float* __restrict__ W_stop,
    const float* __restrict__ b_stop, const uint32_t* __restrict__ keys,
    int t, otype* __restrict__ out) {
  __shared__ float hrow[Hz];
  const int b = blockIdx.x;
  const int j = threadIdx.x;
  const float* gib = gi + (size_t)b * (3 * Hz);
  const float* ghb = gh + (size_t)b * (3 * Hz);
  float ir = gib[j], iz = gib[j + Hz], in_ = gib[j + 2 * Hz];
  float hr = ghb[j], hz = ghb[j + Hz], hn = ghb[j + 2 * Hz];
  float r = 1.0f / (1.0f + expf(-(ir + hr)));
  float z = 1.0f / (1.0f + expf(-(iz + hz)));
  float n = tanhf(in_ + r * hn);
  float hv = h[(size_t)b * Hz + j];
  float hnew = (1.0f - z) * n + z * hv;
  h[(size_t)b * Hz + j] = hnew;
  hrow[j] = hnew;
  __syncthreads();
  if (j < 64) {
    const int lane = j;
    float s = 0.0f;
    for (int k = lane; k < Hz; k += 64) s = fmaf(hrow[k], W_stop[k], s);
#pragma unroll
    for (int off = 32; off; off >>= 1) s += __shfl_down(s, off, 64);
    if (lane == 0) {
      s += b_stop[0];
      uint32_t bits = rand_bits32(keys[t * 4 + 2], keys[t * 4 + 3], (uint32_t)b, Bz);
      float u = bits_to_f01(bits);  // bernoulli: minval=0 -> u = f
      float p = 1.0f / (1.0f + expf(-s));
      float stop = (u < p) ? 1.0f : 0.0f;
      float sp = fmaxf(s, 0.0f) + log1pf(expf(-fabsf(s)));  // softplus
      store_out(out, 1 * BTz + b * Tz + t, stop);
      store_out(out, 3 * BTz + b * Tz + t, stop * s - sp);
      store_out(out, 5 * BTz + b * Tz + t, sp - s * p);
    }
  }
}

// ------- categorical sampling + log_softmax stats + fused emb gather -------
// 1024 threads: pass-1 (threefry+gumbel scan) is 4-way split per tid-residue.
// Valid because pass-1's result is (max, min-index-among-argmax): a
// commutative/associative reduction -> any work partition is bit-identical.
// Pass-2 (Z,S1: order-sensitive sums) runs byte-for-byte unchanged on
// threads 0..255.
__global__ __launch_bounds__(1024) void sample_kernel(const float* __restrict__ logits,
                                                      const uint32_t* __restrict__ keys,
                                                      int t, otype* __restrict__ out,
                                                      const float* __restrict__ emb,
                                                      float* __restrict__ inp) {
  __shared__ float sm4[1024], sg4[1024], sgl4[1024];
  __shared__ int sgi4[1024];
  __shared__ float sm[256], sg[256], sgl[256], sz[256], ss[256];
  __shared__ int sgi[256];
  __shared__ int ssymb;
  const int tid4 = threadIdx.x;
  const int tid = tid4 & 255;   // residue class (pass-2 identity)
  const int sub = tid4 >> 8;    // 4-way split of the residue's v-list
  const int b = blockIdx.x;
  const float* lb = logits + (size_t)b * Vz;
  const uint32_t k1a = keys[t * 4 + 0], k1b = keys[t * 4 + 1];
  const uint32_t base = (uint32_t)b * (uint32_t)Vz;

  float m = -INFINITY, gbest = -INFINITY, glogit = 0.0f;
  int gidx = 0x7FFFFFFF;
  for (int v = tid + (sub << 8); v < Vz; v += 1024) {
    float l = lb[v];
    m = fmaxf(m, l);
    uint32_t bits = rand_bits32(k1a, k1b, base + (uint32_t)v, (uint32_t)Bz * Vz);
    float f = bits_to_f01(bits);
    float u = fmaxf(TINYF, f + TINYF);   // uniform(minval=tiny)
    float g = -logf(-logf(u));           // gumbel
    float val = l + g;
    if (val > gbest) { gbest = val; gidx = v; glogit = l; }
  }
  sm4[tid4] = m; sg4[tid4] = gbest; sgi4[tid4] = gidx; sgl4[tid4] = glogit;
  __syncthreads();
  // fold sub 1..3 into sub 0 with the exact (>, min-idx) rule
  if (tid4 < 256) {
#pragma unroll
    for (int s4 = 1; s4 < 4; s4++) {
      int o = tid4 + (s4 << 8);
      m = fmaxf(m, sm4[o]);
      float go = sg4[o]; int io = sgi4[o];
      if (go > gbest || (go == gbest && io < gidx)) {
        gbest = go; gidx = io; glogit = sgl4[o];
      }
    }
    sm[tid4] = m; sg[tid4] = gbest; sgi[tid4] = gidx; sgl[tid4] = glogit;
  }
  __syncthreads();
  // original 256-tree (unchanged)
  for (int s2 = 128; s2; s2 >>= 1) {
    if (tid4 < s2) {
      sm[tid4] = fmaxf(sm[tid4], sm[tid4 + s2]);
      float go = sg[tid4 + s2]; int io = sgi[tid4 + s2];
      if (go > sg[tid4] || (go == sg[tid4] && io < sgi[tid4])) {
        sg[tid4] = go; sgi[tid4] = io; sgl[tid4] = sgl[tid4 + s2];
      }
    }
    __syncthreads();
  }
  const float M = sm[0];

  // pass 2: order-sensitive sums, byte-for-byte original on threads 0..255
  if (tid4 < 256) {
    float Z = 0.0f, S1 = 0.0f;
    for (int v = tid4; v < Vz; v += 256) {
      float sft = lb[v] - M;
      float e = expf(sft);
      Z += e;
      S1 = fmaf(e, sft, S1);
    }
    sz[tid4] = Z; ss[tid4] = S1;
  }
  __syncthreads();
  for (int s2 = 128; s2; s2 >>= 1) {
    if (tid4 < s2) { sz[tid4] += sz[tid4 + s2]; ss[tid4] += ss[tid4 + s2]; }
    __syncthreads();
  }
  if (tid4 == 0) {
    float Zt = sz[0], S1t = ss[0];
    float lse = logf(Zt);
    int symb = sgi[0];
    store_out(out, 0 * BTz + b * Tz + t, (float)symb);
    store_out(out, 2 * BTz + b * Tz + t, (sgl[0] - M) - lse);
    store_out(out, 4 * BTz + b * Tz + t, lse - S1t / Zt);
    ssymb = symb;
  }
  __syncthreads();
  if (tid4 < Ez) {
    int s = ssymb;
    s = (s < 0) ? 0 : ((s >= Vz) ? (Vz - 1) : s);
    inp[(size_t)b * Ez + tid4] = emb[(size_t)s * Ez + tid4];
  }
}

// ---------------- misc ----------------
__global__ void init_inp_kernel(float* __restrict__ inp, const float* __restrict__ sos) {
  inp[blockIdx.x * Ez + threadIdx.x] = sos[threadIdx.x];
}

// ---------------- launch ----------------
extern "C" __attribute__((visibility("default")))
void kernel_launch(void* const* d_in, const int* in_sizes, int n_in,
                   void* d_out, int out_size, void* d_ws, size_t ws_size,
                   hipStream_t stream) {
  const float* x       = (const float*)d_in[0];
  const float* agent_w = (const float*)d_in[1];
  const float* agent_b = (const float*)d_in[2];
  const float* sos     = (const float*)d_in[3];
  const float* emb     = (const float*)d_in[4];
  const float* W_ih    = (const float*)d_in[5];
  const float* W_hh    = (const float*)d_in[6];
  const float* b_ih    = (const float*)d_in[7];
  const float* b_hh    = (const float*)d_in[8];
  const float* W_out   = (const float*)d_in[9];
  const float* b_out   = (const float*)d_in[10];
  const float* W_stop  = (const float*)d_in[11];
  const float* b_stop  = (const float*)d_in[12];
  otype* out = (otype*)d_out;

  float* ws = (float*)d_ws;
  float* h      = ws;
  float* inp    = h + (size_t)Bz * Hz;
  float* gi     = inp + (size_t)Bz * Ez;
  float* gh     = gi + (size_t)Bz * 3 * Hz;
  float* logits = gh + (size_t)Bz * 3 * Hz;
  uint32_t* keys = (uint32_t*)(logits + (size_t)Bz * Vz);

  keys_kernel<<<1, 64, 0, stream>>>(keys);
  init_inp_kernel<<<Bz, Ez, 0, stream>>>(inp, sos);
  gemm_bt<<<dim3(Hz / GBN, Bz / GBM), 256, 0, stream>>>(x, agent_w, agent_b, h,
                                                        Bz, Hz, INz);
  for (int t = 0; t < Tz; t++) {
    gru2_kernel<<<dim3(3 * Hz / GBN, Bz / GBM, 2), 256, 0, stream>>>(
        inp, W_ih, b_ih, gi, h, W_hh, b_hh, gh);
    gates_stop_kernel<<<Bz, 512, 0, stream>>>(gi, gh, h, W_stop, b_stop, keys,
                                              t, out);
    gemm256_bt<<<(Vz / QBN) * (Bz / QBM), 512, 0, stream>>>(h, W_out, b_out,
                                                            logits, Bz, Vz, Hz);
    sample_kernel<<<Bz, 1024, 0, stream>>>(logits, keys, t, out, emb, inp);
  }
}